// Round 4
// baseline (18715.062 us; speedup 1.0000x reference)
//
#include <hip/hip_runtime.h>
#include <cstddef>

#define BATCH 64
#define CH    64
#define HH    56
#define WW    56
#define HWSZ  3136
#define GN_EPS 1e-5f

// ---------------------------------------------------------------------------
// Per-(b,c)-plane GroupNorm stats of x = srcA + alpha*srcB (srcB nullable).
// Emits scsh[bc] = (sc, sh) with  gn(x) = x*sc + sh.
// ---------------------------------------------------------------------------
__global__ __launch_bounds__(256) void gn_stats_kernel(
    const float* __restrict__ srcA, const float* __restrict__ srcB, float alpha,
    const float* __restrict__ gamma, const float* __restrict__ beta,
    float2* __restrict__ scsh)
{
    const int bc = blockIdx.x;
    const int c  = bc & (CH - 1);
    const size_t base = (size_t)bc * HWSZ;
    const int t = threadIdx.x;

    float s = 0.f, s2 = 0.f;
    if (srcB) {
        for (int i = t; i < HWSZ; i += 256) {
            float x = srcA[base + i] + alpha * srcB[base + i];
            s += x; s2 += x * x;
        }
    } else {
        for (int i = t; i < HWSZ; i += 256) {
            float x = srcA[base + i];
            s += x; s2 += x * x;
        }
    }
#pragma unroll
    for (int off = 32; off > 0; off >>= 1) {
        s  += __shfl_down(s,  off);
        s2 += __shfl_down(s2, off);
    }
    __shared__ float rs[4], rq[4];
    if ((t & 63) == 0) { rs[t >> 6] = s; rq[t >> 6] = s2; }
    __syncthreads();
    if (t == 0) {
        float S  = rs[0] + rs[1] + rs[2] + rs[3];
        float S2 = rq[0] + rq[1] + rq[2] + rq[3];
        const float invn = 1.f / (float)HWSZ;
        float mu  = S * invn;
        float var = S2 * invn - mu * mu;
        float inv = rsqrtf(var + GN_EPS);
        float sc = gamma[c] * inv;
        float sh = beta[c] - mu * sc;
        scsh[bc] = make_float2(sc, sh);
    }
}

// ---------------------------------------------------------------------------
// 3x3 conv (stride 1, pad 1, NCHW, 64ch) with GN+ReLU applied to the input
// DURING LDS staging:  staged = relu((src + salpha*srcK)*sc + sh).
// Optional fused residual: dst = conv + resZ + ralpha*resK  (indices aligned
// with the output, so dst may alias resK element-wise — same thread reads
// before it writes; blocks touch disjoint output indices).
// Optional fused RK4 accumulate: accp = (accinit? 0 : accp) + wk*dstvalue.
// Block: (batch, 4 output rows, 32 output channels). 4 c_in chunks of 16.
// LDS: in_s[16][6][58] + w_s[32][145] = 40,832 B  (< 64 KB).
// ---------------------------------------------------------------------------
__global__ __launch_bounds__(256) void conv3x3_gn_kernel(
    const float* __restrict__ src, const float* __restrict__ srcK, float salpha,
    const float2* __restrict__ scsh, const float* __restrict__ wgt,
    const float* __restrict__ resZ, const float* __restrict__ resK, float ralpha,
    float* __restrict__ accp, float wk, int accinit,
    float* __restrict__ dst)
{
    __shared__ float in_s[16 * 6 * 58];   // ci*348 + r*58 + (cx+1)
    __shared__ float w_s[32 * 145];       // co*145 + (ci_local*9 + k)

    const int t = threadIdx.x;
    int bid = blockIdx.x;
    const int half = bid & 1;  bid >>= 1;
    const int rt = bid % 14;
    const int b  = bid / 14;
    const int h_base = rt * 4;
    const int co_blk = half * 32;

    const int cog  = t & 7;          // c_out group of 4
    const int pg   = t >> 3;
    const int row  = pg >> 3;        // 0..3
    const int colb = (pg & 7) * 7;   // 0,7,...,49
    const int co0  = cog * 4;

    float acc[4][7];
#pragma unroll
    for (int i = 0; i < 4; ++i)
#pragma unroll
        for (int j = 0; j < 7; ++j) acc[i][j] = 0.f;

    for (int cc = 0; cc < 4; ++cc) {
        if (cc) __syncthreads();
        const int cibase = cc * 16;
        // ---- stage input tile with fused GN+ReLU ----
        for (int i = t; i < 16 * 348; i += 256) {
            int ci  = i / 348;
            int rem = i - ci * 348;
            int r   = rem / 58;
            int cx  = rem - r * 58 - 1;
            int gh  = h_base - 1 + r;
            float v = 0.f;
            if (cx >= 0 && cx < WW && gh >= 0 && gh < HH) {
                int plane = b * CH + cibase + ci;
                size_t idx = (size_t)plane * HWSZ + gh * WW + cx;
                v = src[idx];
                if (srcK) v += salpha * srcK[idx];
                float2 ss = scsh[plane];
                v = v * ss.x + ss.y;
                v = v > 0.f ? v : 0.f;
            }
            in_s[i] = v;
        }
        // ---- stage weights for this (c_out half, c_in chunk) ----
        for (int i = t; i < 32 * 144; i += 256) {
            int co = i / 144;
            int rk = i - co * 144;
            w_s[co * 145 + rk] = wgt[(size_t)(co_blk + co) * 576 + cibase * 9 + rk];
        }
        __syncthreads();

        for (int ci = 0; ci < 16; ++ci) {
#pragma unroll
            for (int r = 0; r < 3; ++r) {
                const float* ip = &in_s[ci * 348 + (row + r) * 58 + colb];
                float xv[9];
#pragma unroll
                for (int j = 0; j < 9; ++j) xv[j] = ip[j];
#pragma unroll
                for (int s = 0; s < 3; ++s) {
                    const int rk = ci * 9 + r * 3 + s;
                    float w0 = w_s[(co0 + 0) * 145 + rk];
                    float w1 = w_s[(co0 + 1) * 145 + rk];
                    float w2 = w_s[(co0 + 2) * 145 + rk];
                    float w3 = w_s[(co0 + 3) * 145 + rk];
#pragma unroll
                    for (int px = 0; px < 7; ++px) {
                        float x = xv[px + s];
                        acc[0][px] += w0 * x;
                        acc[1][px] += w1 * x;
                        acc[2][px] += w2 * x;
                        acc[3][px] += w3 * x;
                    }
                }
            }
        }
    }

    const int orow = h_base + row;
#pragma unroll
    for (int j2 = 0; j2 < 4; ++j2) {
        const int co = co_blk + co0 + j2;
        size_t base = (((size_t)b * CH + co) * HH + orow) * WW + colb;
#pragma unroll
        for (int px = 0; px < 7; ++px) {
            float v = acc[j2][px];
            if (resZ) {
                v += resZ[base + px];
                if (resK) v += ralpha * resK[base + px];
            }
            if (accp) {
                float a = wk * v;
                if (!accinit) a += accp[base + px];
                accp[base + px] = a;
            }
            dst[base + px] = v;
        }
    }
}

// ---------------------------------------------------------------------------
// dst = z + c6 * (acc + k)     (float4; dst may alias z or k element-wise)
// ---------------------------------------------------------------------------
__global__ __launch_bounds__(256) void ew_final_kernel(
    const float* __restrict__ z, const float* __restrict__ k,
    const float* __restrict__ acc, float* __restrict__ dst,
    float c6, int n4)
{
    const float4* z4 = (const float4*)z;
    const float4* k4 = (const float4*)k;
    const float4* a4 = (const float4*)acc;
    float4* o4 = (float4*)dst;
    for (int i = blockIdx.x * blockDim.x + threadIdx.x; i < n4;
         i += gridDim.x * blockDim.x) {
        float4 zv = z4[i], kv = k4[i], av = a4[i];
        o4[i] = make_float4(zv.x + c6 * (av.x + kv.x),
                            zv.y + c6 * (av.y + kv.y),
                            zv.z + c6 * (av.z + kv.z),
                            zv.w + c6 * (av.w + kv.w));
    }
}

// ---------------------------------------------------------------------------
extern "C" void kernel_launch(void* const* d_in, const int* in_sizes, int n_in,
                              void* d_out, int out_size, void* d_ws, size_t ws_size,
                              hipStream_t stream)
{
    const float* x  = (const float*)d_in[0];
    const float* g1 = (const float*)d_in[1];
    const float* b1 = (const float*)d_in[2];
    const float* w1 = (const float*)d_in[3];
    const float* g2 = (const float*)d_in[4];
    const float* b2 = (const float*)d_in[5];
    const float* w2 = (const float*)d_in[6];
    float* out = (float*)d_out;               // holds k_i between kernels

    const size_t N = (size_t)BATCH * CH * HH * WW;   // 12,845,056
    float* base  = (float*)d_ws;
    float2* scsh1 = (float2*)base;                   // 4096 float2 = 32 KB
    float2* scsh2 = (float2*)(base + 8192);          // 4096 float2 = 32 KB
    float* z   = base + 16384;                       // RK4 state
    float* acc = z + N;                              // k1+2k2+2k3 accumulator
    float* h;                                        // conv1 raw output
    const size_t need = (size_t)(16384 + 3 * N) * sizeof(float);
    if (ws_size >= need) {
        h = acc + N;
    } else {
        // x is dead after the initial copy; the harness restores inputs from
        // pristine copies before every timed launch, so this buffer is usable
        // as scratch within a launch.
        h = (float*)d_in[0];
    }

    const float dt = 0.125f;
    const int n4 = (int)(N / 4);
    const float alphas[4] = {0.f, 0.5f * dt, 0.5f * dt, dt};
    const float wks[4]    = {1.f, 2.f, 2.f, 0.f};

    hipMemcpyAsync(z, x, N * sizeof(float), hipMemcpyDeviceToDevice, stream);

    const dim3 stG(BATCH * CH), stB(256);
    const dim3 cvG(BATCH * 14 * 2), cvB(256);
    const dim3 ewG(2048), ewB(256);

    for (int step = 0; step < 8; ++step) {
        for (int e = 0; e < 4; ++e) {
            const float a = alphas[e];
            const float* kprev = (e == 0) ? nullptr : out;
            // eval input x_e = z + a*k_prev (never materialized)
            gn_stats_kernel<<<stG, stB, 0, stream>>>(z, kprev, a, g1, b1, scsh1);
            conv3x3_gn_kernel<<<cvG, cvB, 0, stream>>>(
                z, kprev, a, scsh1, w1, nullptr, nullptr, 0.f,
                nullptr, 0.f, 0, h);
            gn_stats_kernel<<<stG, stB, 0, stream>>>(h, nullptr, 0.f, g2, b2, scsh2);
            // k_e -> out (element-wise in place over k_prev), RK4 acc fused
            conv3x3_gn_kernel<<<cvG, cvB, 0, stream>>>(
                h, nullptr, 0.f, scsh2, w2, z, kprev, a,
                (e < 3) ? acc : nullptr, wks[e], e == 0, out);
        }
        ew_final_kernel<<<ewG, ewB, 0, stream>>>(
            z, out, acc, (step == 7) ? out : z, dt / 6.f, n4);
    }
}

// Round 11
// 10517.731 us; speedup vs baseline: 1.7794x; 1.7794x over previous
//
#include <hip/hip_runtime.h>
#include <cstddef>
#include <cstdint>

#define BATCH 64
#define CH    64
#define HH    56
#define WW    56
#define HWSZ  3136
#define GN_EPS 1e-5f
#define WSCALE 64.0f

typedef _Float16 half8  __attribute__((ext_vector_type(8)));
typedef _Float16 half2v __attribute__((ext_vector_type(2)));
typedef float    f32x4  __attribute__((ext_vector_type(4)));

// ---------------------------------------------------------------------------
// Per-(b,c)-plane GroupNorm stats of x = srcA + alpha*srcB (srcB nullable).
// Emits scsh[bc] = (sc, sh) with  gn(x) = x*sc + sh.   (verified round 4)
// ---------------------------------------------------------------------------
__global__ __launch_bounds__(256) void gn_stats_kernel(
    const float* __restrict__ srcA, const float* __restrict__ srcB, float alpha,
    const float* __restrict__ gamma, const float* __restrict__ beta,
    float2* __restrict__ scsh)
{
    const int bc = blockIdx.x;
    const int c  = bc & (CH - 1);
    const size_t base = (size_t)bc * HWSZ;
    const int t = threadIdx.x;

    float s = 0.f, s2 = 0.f;
    if (srcB) {
        for (int i = t; i < HWSZ; i += 256) {
            float x = srcA[base + i] + alpha * srcB[base + i];
            s += x; s2 += x * x;
        }
    } else {
        for (int i = t; i < HWSZ; i += 256) {
            float x = srcA[base + i];
            s += x; s2 += x * x;
        }
    }
#pragma unroll
    for (int off = 32; off > 0; off >>= 1) {
        s  += __shfl_down(s,  off);
        s2 += __shfl_down(s2, off);
    }
    __shared__ float rs[4], rq[4];
    if ((t & 63) == 0) { rs[t >> 6] = s; rq[t >> 6] = s2; }
    __syncthreads();
    if (t == 0) {
        float S  = rs[0] + rs[1] + rs[2] + rs[3];
        float S2 = rq[0] + rq[1] + rq[2] + rq[3];
        const float invn = 1.f / (float)HWSZ;
        float mu  = S * invn;
        float var = S2 * invn - mu * mu;
        float inv = rsqrtf(var + GN_EPS);
        float sc = gamma[c] * inv;
        float sh = beta[c] - mu * sc;
        scsh[bc] = make_float2(sc, sh);
    }
}

// ---------------------------------------------------------------------------
// Weight prep: fp32 OIHW -> (w*64) split into fp16 hi/lo (both normal-range),
// layout [conv][part][tap][co][ci]. Same work every call; graph-safe.
// ---------------------------------------------------------------------------
__global__ __launch_bounds__(256) void wprep_kernel(
    const float* __restrict__ w1, const float* __restrict__ w2,
    _Float16* __restrict__ wT)
{
    int i = blockIdx.x * 256 + threadIdx.x;          // over 2*9*64*64
    if (i >= 2 * 9 * 64 * 64) return;
    int ci   = i & 63;
    int co   = (i >> 6) & 63;
    int rest = i >> 12;                              // 0..17
    int tap  = rest % 9;
    int conv = rest / 9;
    const float* w = conv ? w2 : w1;
    float v = w[(co * 64 + ci) * 9 + tap] * WSCALE;
    _Float16 hi = (_Float16)v;
    _Float16 lo = (_Float16)(v - (float)hi);
    wT[((size_t)(conv * 2 + 0) * 9 + tap) * 4096 + co * 64 + ci] = hi;
    wT[((size_t)(conv * 2 + 1) * 9 + tap) * 4096 + co * 64 + ci] = lo;
}

// ---------------------------------------------------------------------------
// 3x3 conv via MFMA implicit GEMM, fp16 hi/lo split (3 MFMA per tap-chunk):
//   out = W*relu(gn(src + salpha*srcK))  [+ resZ + ralpha*resK]
//   optional RK4 accumulate: accp = (accinit?0:accp) + wk*out
// Block = (batch, 4 output rows, all 64 co). 8 waves = 4 co-tiles x 2 row
// pairs. A (weights, pre-scaled x64) reg-resident per 32-ci chunk; input
// staged in LDS as [part][r(6)][hc(66)][ci(40-pitch)] fp16 so each lane's
// B-frag (8 consecutive ci at one pixel) is one 16B ds_read_b128. Pitch 40
// halves = 80 B -> read banks step 20 mod 32 (2-way, free). LDS 63,360 B.
// C/D layout (m89): col=lane&15 (pixel), row=(lane>>4)*4+reg (co offset).
// ---------------------------------------------------------------------------
__global__ __launch_bounds__(512, 2) void conv3x3_mfma_kernel(
    const float* __restrict__ src, const float* __restrict__ srcK, float salpha,
    const float2* __restrict__ scsh, const _Float16* __restrict__ wTc,
    const float* __restrict__ resZ, const float* __restrict__ resK, float ralpha,
    float* __restrict__ accp, float wk, int accinit,
    float* __restrict__ dst)
{
    constexpr int PITCH = 40;                 // halves per (r,hc) ci-row
    constexpr int PART  = 6 * 66 * PITCH;     // 15840 halves per part
    __shared__ __align__(16) _Float16 xs[2 * PART];   // 63,360 B

    const int t  = threadIdx.x;
    const int b  = blockIdx.x / 14;
    const int rt = blockIdx.x % 14;
    const int h0 = rt * 4;

    const int wave = t >> 6;
    const int l    = t & 63;
    const int lrow = l & 15;     // A row (co offset) / B col (pixel)
    const int g    = l >> 4;     // k-group (8 ci per group)
    const int wm   = wave & 3;   // co tile
    const int wn   = wave >> 2;  // row pair
    const int co0  = wm * 16;

    f32x4 acc[2][4];
#pragma unroll
    for (int i = 0; i < 2; ++i)
#pragma unroll
        for (int j = 0; j < 4; ++j) acc[i][j] = f32x4{0.f, 0.f, 0.f, 0.f};

#pragma unroll
    for (int cc = 0; cc < 2; ++cc) {
        // ---- weight A-frags for this 32-ci chunk (issue early) ----
        half8 wf[2][9];
#pragma unroll
        for (int part = 0; part < 2; ++part)
#pragma unroll
            for (int tap = 0; tap < 9; ++tap) {
                const _Float16* p = wTc +
                    ((size_t)(part * 9 + tap) * 64 + co0 + lrow) * 64 + cc * 32 + 8 * g;
                wf[part][tap] = *(const half8*)p;
            }

        if (cc) __syncthreads();
        // ---- stage 32-ci chunk (ci-pairs) with fused GN+ReLU, hi/lo ----
        for (int i = t; i < 16 * 396; i += 512) {
            int cp  = i / 396;               // ci pair (0..15)
            int rem = i - cp * 396;
            int r   = rem / 66;
            int hc  = rem - r * 66;
            int gh = h0 - 1 + r, gc = hc - 1;
            float v0 = 0.f, v1 = 0.f;
            if (gc >= 0 && gc < WW && gh >= 0 && gh < HH) {
                int plane0 = b * CH + cc * 32 + 2 * cp;
                size_t idx0 = (size_t)plane0 * HWSZ + gh * WW + gc;
                v0 = src[idx0];
                v1 = src[idx0 + HWSZ];
                if (srcK) {
                    v0 += salpha * srcK[idx0];
                    v1 += salpha * srcK[idx0 + HWSZ];
                }
                float2 s0 = scsh[plane0], s1 = scsh[plane0 + 1];
                v0 = v0 * s0.x + s0.y;  v1 = v1 * s1.x + s1.y;
                v0 = v0 > 0.f ? v0 : 0.f;  v1 = v1 > 0.f ? v1 : 0.f;
            }
            _Float16 h0f = (_Float16)v0, h1f = (_Float16)v1;
            _Float16 l0f = (_Float16)(v0 - (float)h0f);
            _Float16 l1f = (_Float16)(v1 - (float)h1f);
            int ad = (r * 66 + hc) * PITCH + 2 * cp;
            *(half2v*)&xs[ad]        = half2v{h0f, h1f};
            *(half2v*)&xs[PART + ad] = half2v{l0f, l1f};
        }
        __syncthreads();

        // ---- MFMA compute ----
#pragma unroll
        for (int ct = 0; ct < 4; ++ct) {
#pragma unroll
            for (int ir = 0; ir < 4; ++ir) {
                const int airr = 2 * wn + ir;           // halo row 0..5
                half8 bh[3], bl[3];
#pragma unroll
                for (int kw = 0; kw < 3; ++kw) {
                    int hc = ct * 16 + lrow + kw;       // halo col 0..65
                    int ad = (airr * 66 + hc) * PITCH + 8 * g;
                    bh[kw] = *(const half8*)&xs[ad];
                    bl[kw] = *(const half8*)&xs[PART + ad];
                }
#pragma unroll
                for (int rl = 0; rl < 2; ++rl) {
                    const int kh = ir - rl;             // tap row
                    if (kh < 0 || kh > 2) continue;
#pragma unroll
                    for (int kw = 0; kw < 3; ++kw) {
                        const int tap = kh * 3 + kw;
                        acc[rl][ct] = __builtin_amdgcn_mfma_f32_16x16x32_f16(
                            wf[0][tap], bh[kw], acc[rl][ct], 0, 0, 0);
                        acc[rl][ct] = __builtin_amdgcn_mfma_f32_16x16x32_f16(
                            wf[1][tap], bh[kw], acc[rl][ct], 0, 0, 0);
                        acc[rl][ct] = __builtin_amdgcn_mfma_f32_16x16x32_f16(
                            wf[0][tap], bl[kw], acc[rl][ct], 0, 0, 0);
                    }
                }
            }
        }
    }

    // ---- epilogue: un-scale + residual + RK4 acc fusion (round-4 logic) ----
    const int orow0 = h0 + 2 * wn;
#pragma unroll
    for (int rl = 0; rl < 2; ++rl) {
#pragma unroll
        for (int ct = 0; ct < 4; ++ct) {
            int col = ct * 16 + lrow;
            if (col < WW) {
#pragma unroll
                for (int i = 0; i < 4; ++i) {
                    int co = co0 + g * 4 + i;
                    size_t idx = ((size_t)(b * CH + co)) * HWSZ + (orow0 + rl) * WW + col;
                    float v = acc[rl][ct][i] * (1.0f / WSCALE);
                    if (resZ) {
                        v += resZ[idx];
                        if (resK) v += ralpha * resK[idx];
                    }
                    if (accp) {
                        float aa = wk * v;
                        if (!accinit) aa += accp[idx];
                        accp[idx] = aa;
                    }
                    dst[idx] = v;
                }
            }
        }
    }
}

// ---------------------------------------------------------------------------
// dst = z + c6 * (acc + k)     (float4; dst may alias z or k element-wise)
// ---------------------------------------------------------------------------
__global__ __launch_bounds__(256) void ew_final_kernel(
    const float* __restrict__ z, const float* __restrict__ k,
    const float* __restrict__ acc, float* __restrict__ dst,
    float c6, int n4)
{
    const float4* z4 = (const float4*)z;
    const float4* k4 = (const float4*)k;
    const float4* a4 = (const float4*)acc;
    float4* o4 = (float4*)dst;
    for (int i = blockIdx.x * blockDim.x + threadIdx.x; i < n4;
         i += gridDim.x * blockDim.x) {
        float4 zv = z4[i], kv = k4[i], av = a4[i];
        o4[i] = make_float4(zv.x + c6 * (av.x + kv.x),
                            zv.y + c6 * (av.y + kv.y),
                            zv.z + c6 * (av.z + kv.z),
                            zv.w + c6 * (av.w + kv.w));
    }
}

// ---------------------------------------------------------------------------
extern "C" void kernel_launch(void* const* d_in, const int* in_sizes, int n_in,
                              void* d_out, int out_size, void* d_ws, size_t ws_size,
                              hipStream_t stream)
{
    const float* x  = (const float*)d_in[0];
    const float* g1 = (const float*)d_in[1];
    const float* b1 = (const float*)d_in[2];
    const float* w1 = (const float*)d_in[3];
    const float* g2 = (const float*)d_in[4];
    const float* b2 = (const float*)d_in[5];
    const float* w2 = (const float*)d_in[6];
    float* out = (float*)d_out;               // holds k_i between kernels

    const size_t N = (size_t)BATCH * CH * HH * WW;   // 12,845,056
    float* base  = (float*)d_ws;
    float2* scsh1 = (float2*)base;                   // 8192 floats
    float2* scsh2 = (float2*)(base + 8192);          // 8192 floats
    _Float16* wT  = (_Float16*)(base + 16384);       // 147456 halves = 73728 floats
    float* z   = base + 16384 + 73728;               // RK4 state
    float* acc = z + N;                              // k1+2k2+2k3 accumulator
    float* h;                                        // conv1 raw output
    const size_t need = (size_t)(16384 + 73728 + 3 * N) * sizeof(float);
    if (ws_size >= need) {
        h = acc + N;
    } else {
        // x is dead after the initial copy; harness restores inputs from
        // pristine copies before every timed launch.
        h = (float*)d_in[0];
    }

    const float dt = 0.125f;
    const int n4 = (int)(N / 4);
    const float alphas[4] = {0.f, 0.5f * dt, 0.5f * dt, dt};
    const float wks[4]    = {1.f, 2.f, 2.f, 0.f};

    wprep_kernel<<<dim3(288), dim3(256), 0, stream>>>(w1, w2, wT);
    hipMemcpyAsync(z, x, N * sizeof(float), hipMemcpyDeviceToDevice, stream);

    const dim3 stG(BATCH * CH), stB(256);
    const dim3 cvG(BATCH * 14), cvB(512);
    const dim3 ewG(2048), ewB(256);

    const _Float16* wT1 = wT;
    const _Float16* wT2 = wT + 73728;

    for (int step = 0; step < 8; ++step) {
        for (int e = 0; e < 4; ++e) {
            const float a = alphas[e];
            const float* kprev = (e == 0) ? nullptr : out;
            // eval input x_e = z + a*k_prev (never materialized)
            gn_stats_kernel<<<stG, stB, 0, stream>>>(z, kprev, a, g1, b1, scsh1);
            conv3x3_mfma_kernel<<<cvG, cvB, 0, stream>>>(
                z, kprev, a, scsh1, wT1, nullptr, nullptr, 0.f,
                nullptr, 0.f, 0, h);
            gn_stats_kernel<<<stG, stB, 0, stream>>>(h, nullptr, 0.f, g2, b2, scsh2);
            // k_e -> out (element-wise in place over k_prev), RK4 acc fused
            conv3x3_mfma_kernel<<<cvG, cvB, 0, stream>>>(
                h, nullptr, 0.f, scsh2, wT2, z, kprev, a,
                (e < 3) ? acc : nullptr, wks[e], e == 0, out);
        }
        ew_final_kernel<<<ewG, ewB, 0, stream>>>(
            z, out, acc, (step == 7) ? out : z, dt / 6.f, n4);
    }
}